// Round 1
// baseline (1919.257 us; speedup 1.0000x reference)
//
#include <hip/hip_runtime.h>

#define HDT 0.05f      // dt/2
#define KSTEPS 8       // Horner/Neumann order: worst-case rel err 0.33^9 ~ 4.6e-5

__device__ __forceinline__ float bf2f(unsigned int u) {
    return __uint_as_float(u << 16);
}
__device__ __forceinline__ unsigned int f2bf(float x) {
    unsigned int b = __float_as_uint(x);
    return (b + 0x7FFFu + ((b >> 16) & 1u)) >> 16;   // RNE
}
__device__ __forceinline__ float rfl(float x) {
    return __int_as_float(__builtin_amdgcn_readfirstlane(__float_as_int(x)));
}

// stencil coefficient slot for signed distance d (compile-time folded)
__host__ __device__ constexpr int cidx(int d) {
    int a = d < 0 ? -d : d;
    return (a==0)?0:(a==1)?1:(a==2)?2:(a==3)?3:(a==4)?4:(a==5)?5:(a==6)?6:
           (a==8)?7:(a==10)?8:(a==12)?9:(a==16)?10:(a==20)?11:-1;
}

// ---- dtype probe: bf16 data's low-16 bits look like bf16 exponents; f32
// data's low-16 bits are ~uniform mantissa bits. ----
__global__ void detect_dtype(const unsigned int* __restrict__ w, int* __restrict__ flag) {
    int cnt = 0;
    for (int i = threadIdx.x; i < 4096; i += 64) {
        unsigned int e = (w[i] >> 7) & 0xFFu;          // exponent field of low-half bf16
        cnt += (e >= 0x78u && e <= 0x82u) ? 1 : 0;     // |x| in [2^-7, 8]
    }
    #pragma unroll
    for (int off = 32; off; off >>= 1) cnt += __shfl_xor(cnt, off, 64);
    if (threadIdx.x == 0) *flag = (cnt > 2048) ? 1 : 0;
}

__global__ __launch_bounds__(256, 3)
void cayley_main(const void* __restrict__ psi_r, const void* __restrict__ psi_i,
                 const void* __restrict__ alpha, const void* __restrict__ ham_w,
                 void* __restrict__ out, const int* __restrict__ flagp)
{
    // 4 systems/block * 2 comps * 256 quads (f32x4) = 32 KB
    __shared__ float4 lds4[2048];

    const int lane = threadIdx.x & 63;
    const int wv   = threadIdx.x >> 6;
    const int sys  = (blockIdx.x << 2) + wv;   // [0, 16384)
    const int sysq = wv << 9;                  // quad base of this system's LDS

    const bool isbf = (*flagp) != 0;

    // ---- combined stencil coefficients (h-scaled), forced to SGPR ----
    float hw[15];
    if (isbf) {
        const unsigned short* p = (const unsigned short*)ham_w;
        #pragma unroll
        for (int i = 0; i < 15; ++i) hw[i] = bf2f((unsigned int)p[i]);
    } else {
        const float* p = (const float*)ham_w;
        #pragma unroll
        for (int i = 0; i < 15; ++i) hw[i] = p[i];
    }
    float cs[12];
    {
        float s = 0.f;
        #pragma unroll
        for (int i = 0; i < 15; ++i) s += hw[i];
        cs[0]  = rfl( 2.f*HDT*s);                       // center: h*2*sum(w)
        cs[1]  = rfl(-HDT* hw[0]);                      // off 1
        cs[2]  = rfl(-HDT*(hw[1]+hw[5]));               // off 2
        cs[3]  = rfl(-HDT* hw[2]);                      // off 3
        cs[4]  = rfl(-HDT*(hw[3]+hw[6]+hw[10]));        // off 4
        cs[5]  = rfl(-HDT* hw[4]);                      // off 5
        cs[6]  = rfl(-HDT* hw[7]);                      // off 6
        cs[7]  = rfl(-HDT*(hw[8]+hw[11]));              // off 8
        cs[8]  = rfl(-HDT* hw[9]);                      // off 10
        cs[9]  = rfl(-HDT* hw[12]);                     // off 12
        cs[10] = rfl(-HDT* hw[13]);                     // off 16
        cs[11] = rfl(-HDT* hw[14]);                     // off 20
    }

    // ---- LDS addresses (quad indices), XOR bank swizzle ----
    int raddr[14];
    #pragma unroll
    for (int g = 0; g < 14; ++g) {
        int qd = (4*lane - 5 + g) & 255;               // window d = 16*lane-20 .. +35
        raddr[g] = sysq + (qd ^ ((qd >> 3) & 7));
    }
    int waddr[4];
    #pragma unroll
    for (int k = 0; k < 4; ++k) {
        int qd = 4*lane + k;
        waddr[k] = sysq + (qd ^ ((qd >> 3) & 7));
    }

    // ---- load psi (16 d's per lane) and alpha ----
    float pr[16], pq[16], al[16];
    if (isbf) {
        const unsigned short* bR = (const unsigned short*)psi_r + (size_t)sys*1024 + lane*16;
        const unsigned short* bI = (const unsigned short*)psi_i + (size_t)sys*1024 + lane*16;
        const unsigned short* bA = (const unsigned short*)alpha  + lane*16;
        #pragma unroll
        for (int h = 0; h < 2; ++h) {
            uint4 a = ((const uint4*)bR)[h];
            uint4 b = ((const uint4*)bI)[h];
            uint4 c = ((const uint4*)bA)[h];
            pr[h*8+0]=bf2f(a.x&0xFFFFu); pr[h*8+1]=bf2f(a.x>>16);
            pr[h*8+2]=bf2f(a.y&0xFFFFu); pr[h*8+3]=bf2f(a.y>>16);
            pr[h*8+4]=bf2f(a.z&0xFFFFu); pr[h*8+5]=bf2f(a.z>>16);
            pr[h*8+6]=bf2f(a.w&0xFFFFu); pr[h*8+7]=bf2f(a.w>>16);
            pq[h*8+0]=bf2f(b.x&0xFFFFu); pq[h*8+1]=bf2f(b.x>>16);
            pq[h*8+2]=bf2f(b.y&0xFFFFu); pq[h*8+3]=bf2f(b.y>>16);
            pq[h*8+4]=bf2f(b.z&0xFFFFu); pq[h*8+5]=bf2f(b.z>>16);
            pq[h*8+6]=bf2f(b.w&0xFFFFu); pq[h*8+7]=bf2f(b.w>>16);
            al[h*8+0]=bf2f(c.x&0xFFFFu); al[h*8+1]=bf2f(c.x>>16);
            al[h*8+2]=bf2f(c.y&0xFFFFu); al[h*8+3]=bf2f(c.y>>16);
            al[h*8+4]=bf2f(c.z&0xFFFFu); al[h*8+5]=bf2f(c.z>>16);
            al[h*8+6]=bf2f(c.w&0xFFFFu); al[h*8+7]=bf2f(c.w>>16);
        }
    } else {
        const float* fR = (const float*)psi_r + (size_t)sys*1024 + lane*16;
        const float* fI = (const float*)psi_i + (size_t)sys*1024 + lane*16;
        const float* fA = (const float*)alpha  + lane*16;
        #pragma unroll
        for (int h = 0; h < 4; ++h) {
            float4 a = ((const float4*)fR)[h];
            float4 b = ((const float4*)fI)[h];
            float4 c = ((const float4*)fA)[h];
            pr[4*h]=a.x; pr[4*h+1]=a.y; pr[4*h+2]=a.z; pr[4*h+3]=a.w;
            pq[4*h]=b.x; pq[4*h+1]=b.y; pq[4*h+2]=b.z; pq[4*h+3]=b.w;
            al[4*h]=c.x; al[4*h+1]=c.y; al[4*h+2]=c.z; al[4*h+3]=c.w;
        }
    }

    // ---- intensity mean (wave reduction; one wave == one system) ----
    float ssum = 0.f;
    #pragma unroll
    for (int k = 0; k < 16; ++k) ssum += pr[k]*pr[k] + pq[k]*pq[k];
    #pragma unroll
    for (int off = 32; off; off >>= 1) ssum += __shfl_xor(ssum, off, 64);
    const float inv = 1.f / (ssum * (1.f/1024.f) + 1e-8f);

    // ---- nonlinear phase rotation ----
    float tr[16], ti[16];
    #pragma unroll
    for (int k = 0; k < 16; ++k) {
        float inten = (pr[k]*pr[k] + pq[k]*pq[k]) * inv;
        float ph = al[k] * inten;
        float cc = __cosf(ph), sn = __sinf(ph);
        tr[k] = pr[k]*cc - pq[k]*sn;
        ti[k] = pr[k]*sn + pq[k]*cc;
    }

    auto ldswrite = [&](const float* xr, const float* xi) {
        #pragma unroll
        for (int k = 0; k < 4; ++k) {
            lds4[waddr[k]]       = make_float4(xr[4*k], xr[4*k+1], xr[4*k+2], xr[4*k+3]);
            lds4[waddr[k] + 256] = make_float4(xi[4*k], xi[4*k+1], xi[4*k+2], xi[4*k+3]);
        }
    };

    // hr/hi2 = (h*H) applied to LDS-resident vector, per comp
    float hr[16], hi2[16];
    auto stencil = [&]() {
        #pragma unroll
        for (int k = 0; k < 16; ++k) { hr[k] = 0.f; hi2[k] = 0.f; }
        #pragma unroll
        for (int g = 0; g < 14; ++g) {
            float4 qr = lds4[raddr[g]];
            float4 qi = lds4[raddr[g] + 256];
            float er[4] = {qr.x, qr.y, qr.z, qr.w};
            float ei[4] = {qi.x, qi.y, qi.z, qi.w};
            #pragma unroll
            for (int e = 0; e < 4; ++e) {
                const int j = 4*g + e;          // window float index; d = 16*lane-20+j
                #pragma unroll
                for (int k = 0; k < 16; ++k) {
                    const int id = cidx(j - 20 - k);
                    if (id >= 0) {
                        hr[k]  = fmaf(cs[id], er[e], hr[k]);
                        hi2[k] = fmaf(cs[id], ei[e], hi2[k]);
                    }
                }
            }
        }
    };

    // rot -> LDS
    ldswrite(tr, ti);
    __syncthreads();

    // rhs b = (I - i*h*H) rot : b_r = rot_r + hH(rot_i) ; b_i = rot_i - hH(rot_r)
    stencil();
    float br[16], bi[16];
    #pragma unroll
    for (int k = 0; k < 16; ++k) { br[k] = tr[k] + hi2[k]; bi[k] = ti[k] - hr[k]; }
    __syncthreads();
    ldswrite(br, bi);          // t0 = b
    __syncthreads();

    // Horner: t <- b - i*h*H t  ==> t_r = b_r + hH(t_i), t_i = b_i - hH(t_r)
    #pragma unroll 1
    for (int itn = 0; itn < KSTEPS; ++itn) {
        stencil();
        #pragma unroll
        for (int k = 0; k < 16; ++k) { tr[k] = br[k] + hi2[k]; ti[k] = bi[k] - hr[k]; }
        if (itn != KSTEPS - 1) {
            __syncthreads();
            ldswrite(tr, ti);
            __syncthreads();
        }
    }

    // ---- store interleaved (r,i) pairs ----
    if (isbf) {
        unsigned short* po = (unsigned short*)out + (size_t)sys*2048 + lane*32;
        uint4* po4 = (uint4*)po;
        #pragma unroll
        for (int h = 0; h < 4; ++h) {
            uint4 v;
            v.x = f2bf(tr[4*h+0]) | (f2bf(ti[4*h+0]) << 16);
            v.y = f2bf(tr[4*h+1]) | (f2bf(ti[4*h+1]) << 16);
            v.z = f2bf(tr[4*h+2]) | (f2bf(ti[4*h+2]) << 16);
            v.w = f2bf(tr[4*h+3]) | (f2bf(ti[4*h+3]) << 16);
            po4[h] = v;
        }
    } else {
        float* po = (float*)out + (size_t)sys*2048 + lane*32;
        #pragma unroll
        for (int k = 0; k < 8; ++k) {
            *(float4*)(po + 4*k) = make_float4(tr[2*k], ti[2*k], tr[2*k+1], ti[2*k+1]);
        }
    }
}

extern "C" void kernel_launch(void* const* d_in, const int* in_sizes, int n_in,
                              void* d_out, int out_size, void* d_ws, size_t ws_size,
                              hipStream_t stream)
{
    (void)in_sizes; (void)n_in; (void)out_size; (void)ws_size;
    detect_dtype<<<dim3(1), dim3(64), 0, stream>>>((const unsigned int*)d_in[0], (int*)d_ws);
    cayley_main<<<dim3(4096), dim3(256), 0, stream>>>(d_in[0], d_in[1], d_in[2], d_in[3],
                                                      d_out, (const int*)d_ws);
}

// Round 3
// 302.215 us; speedup vs baseline: 6.3506x; 6.3506x over previous
//
#include <hip/hip_runtime.h>
#include <utility>

typedef float v2f __attribute__((ext_vector_type(2)));

#define HDT 0.05f      // dt/2
#define KSTEPS 5       // Horner order: worst-case rel err 0.33^6 ~ 1.3e-3 << bf16 ULP

__device__ __forceinline__ float bf2f(unsigned int u) {
    return __uint_as_float(u << 16);
}
__device__ __forceinline__ unsigned int f2bf(float x) {
    unsigned int b = __float_as_uint(x);
    return (b + 0x7FFFu + ((b >> 16) & 1u)) >> 16;   // RNE
}
__device__ __forceinline__ float rfl(float x) {
    return __int_as_float(__builtin_amdgcn_readfirstlane(__float_as_int(x)));
}

// compile-time for: f(integral_constant<int,I>) for I in [0,N)
template <int... Is, class F>
__device__ __forceinline__ void static_for_impl(std::integer_sequence<int, Is...>, F&& f) {
    (f(std::integral_constant<int, Is>{}), ...);
}
template <int N, class F>
__device__ __forceinline__ void static_for(F&& f) {
    static_for_impl(std::make_integer_sequence<int, N>{}, (F&&)f);
}

// stencil coefficient slot for signed distance d (compile-time)
__host__ __device__ constexpr int cidx(int d) {
    int a = d < 0 ? -d : d;
    return (a==0)?0:(a==1)?1:(a==2)?2:(a==3)?3:(a==4)?4:(a==5)?5:(a==6)?6:
           (a==8)?7:(a==10)?8:(a==12)?9:(a==16)?10:(a==20)?11:-1;
}

// ---- dtype probe: bf16 data's low-16 bits look like bf16 exponents ----
__global__ void detect_dtype(const unsigned int* __restrict__ w, int* __restrict__ flag) {
    int cnt = 0;
    for (int i = threadIdx.x; i < 4096; i += 64) {
        unsigned int e = (w[i] >> 7) & 0xFFu;
        cnt += (e >= 0x78u && e <= 0x82u) ? 1 : 0;
    }
    #pragma unroll
    for (int off = 32; off; off >>= 1) cnt += __shfl_xor(cnt, off, 64);
    if (threadIdx.x == 0) *flag = (cnt > 2048) ? 1 : 0;
}

__global__ __launch_bounds__(256, 3)
void cayley_main(const void* __restrict__ psi_r, const void* __restrict__ psi_i,
                 const void* __restrict__ alpha, const void* __restrict__ ham_w,
                 void* __restrict__ out, const int* __restrict__ flagp)
{
    // 4 systems/block * 512 quads (float4 = 2 complex pts) = 32 KB
    __shared__ float4 lds4[2048];

    const int lane = threadIdx.x & 63;
    const int wv   = threadIdx.x >> 6;
    const int sys  = (blockIdx.x << 2) + wv;   // [0, 16384)
    const int sysq = wv << 9;                  // quad base (512 quads/system)

    const bool isbf = (*flagp) != 0;

    // ---- combined stencil coefficients (h-scaled), forced to SGPR ----
    float hw[15];
    if (isbf) {
        const unsigned short* p = (const unsigned short*)ham_w;
        #pragma unroll
        for (int i = 0; i < 15; ++i) hw[i] = bf2f((unsigned int)p[i]);
    } else {
        const float* p = (const float*)ham_w;
        #pragma unroll
        for (int i = 0; i < 15; ++i) hw[i] = p[i];
    }
    float cs[12];
    {
        float s = 0.f;
        #pragma unroll
        for (int i = 0; i < 15; ++i) s += hw[i];
        cs[0]  = rfl( 2.f*HDT*s);                       // center
        cs[1]  = rfl(-HDT* hw[0]);                      // off 1
        cs[2]  = rfl(-HDT*(hw[1]+hw[5]));               // off 2
        cs[3]  = rfl(-HDT* hw[2]);                      // off 3
        cs[4]  = rfl(-HDT*(hw[3]+hw[6]+hw[10]));        // off 4
        cs[5]  = rfl(-HDT* hw[4]);                      // off 5
        cs[6]  = rfl(-HDT* hw[7]);                      // off 6
        cs[7]  = rfl(-HDT*(hw[8]+hw[11]));              // off 8
        cs[8]  = rfl(-HDT* hw[9]);                      // off 10
        cs[9]  = rfl(-HDT* hw[12]);                     // off 12
        cs[10] = rfl(-HDT* hw[13]);                     // off 16
        cs[11] = rfl(-HDT* hw[14]);                     // off 20
    }

    // ---- LDS addresses (quad indices), XOR bank swizzle ----
    // read window: points 16L-20 .. 16L+35 = quads 8L-10 .. 8L+17 (28 quads)
    int raddr[28];
    #pragma unroll
    for (int g = 0; g < 28; ++g) {
        int qd = (8*lane - 10 + g) & 511;
        raddr[g] = sysq + (qd ^ ((qd >> 3) & 7));
    }
    int waddr[8];
    #pragma unroll
    for (int k = 0; k < 8; ++k) {
        int qd = 8*lane + k;
        waddr[k] = sysq + (qd ^ ((qd >> 3) & 7));
    }

    // ---- load psi (16 points per lane) and alpha ----
    float pr[16], pq[16], al[16];
    if (isbf) {
        const unsigned short* bR = (const unsigned short*)psi_r + (size_t)sys*1024 + lane*16;
        const unsigned short* bI = (const unsigned short*)psi_i + (size_t)sys*1024 + lane*16;
        const unsigned short* bA = (const unsigned short*)alpha  + lane*16;
        static_for<2>([&](auto hI) {
            constexpr int h = hI.value;
            uint4 a = ((const uint4*)bR)[h];
            uint4 b = ((const uint4*)bI)[h];
            uint4 c = ((const uint4*)bA)[h];
            pr[h*8+0]=bf2f(a.x&0xFFFFu); pr[h*8+1]=bf2f(a.x>>16);
            pr[h*8+2]=bf2f(a.y&0xFFFFu); pr[h*8+3]=bf2f(a.y>>16);
            pr[h*8+4]=bf2f(a.z&0xFFFFu); pr[h*8+5]=bf2f(a.z>>16);
            pr[h*8+6]=bf2f(a.w&0xFFFFu); pr[h*8+7]=bf2f(a.w>>16);
            pq[h*8+0]=bf2f(b.x&0xFFFFu); pq[h*8+1]=bf2f(b.x>>16);
            pq[h*8+2]=bf2f(b.y&0xFFFFu); pq[h*8+3]=bf2f(b.y>>16);
            pq[h*8+4]=bf2f(b.z&0xFFFFu); pq[h*8+5]=bf2f(b.z>>16);
            pq[h*8+6]=bf2f(b.w&0xFFFFu); pq[h*8+7]=bf2f(b.w>>16);
            al[h*8+0]=bf2f(c.x&0xFFFFu); al[h*8+1]=bf2f(c.x>>16);
            al[h*8+2]=bf2f(c.y&0xFFFFu); al[h*8+3]=bf2f(c.y>>16);
            al[h*8+4]=bf2f(c.z&0xFFFFu); al[h*8+5]=bf2f(c.z>>16);
            al[h*8+6]=bf2f(c.w&0xFFFFu); al[h*8+7]=bf2f(c.w>>16);
        });
    } else {
        const float* fR = (const float*)psi_r + (size_t)sys*1024 + lane*16;
        const float* fI = (const float*)psi_i + (size_t)sys*1024 + lane*16;
        const float* fA = (const float*)alpha  + lane*16;
        static_for<4>([&](auto hI) {
            constexpr int h = hI.value;
            float4 a = ((const float4*)fR)[h];
            float4 b = ((const float4*)fI)[h];
            float4 c = ((const float4*)fA)[h];
            pr[4*h]=a.x; pr[4*h+1]=a.y; pr[4*h+2]=a.z; pr[4*h+3]=a.w;
            pq[4*h]=b.x; pq[4*h+1]=b.y; pq[4*h+2]=b.z; pq[4*h+3]=b.w;
            al[4*h]=c.x; al[4*h+1]=c.y; al[4*h+2]=c.z; al[4*h+3]=c.w;
        });
    }

    // ---- intensity mean (wave reduction; one wave == one system) ----
    float ssum = 0.f;
    #pragma unroll
    for (int k = 0; k < 16; ++k) ssum += pr[k]*pr[k] + pq[k]*pq[k];
    #pragma unroll
    for (int off = 32; off; off >>= 1) ssum += __shfl_xor(ssum, off, 64);
    const float inv = 1.f / (ssum * (1.f/1024.f) + 1e-8f);

    // ---- nonlinear phase rotation -> cur ----
    v2f cur[16];
    static_for<16>([&](auto kI) {
        constexpr int k = kI.value;
        float inten = (pr[k]*pr[k] + pq[k]*pq[k]) * inv;
        float ph = al[k] * inten;
        float cc = __cosf(ph), sn = __sinf(ph);
        cur[k].x = pr[k]*cc - pq[k]*sn;
        cur[k].y = pr[k]*sn + pq[k]*cc;
    });

    v2f acc[16], b[16], t[16];

    // All LDS traffic is wave-private (own 8KB region) -> no __syncthreads;
    // per-wave lgkmcnt ordering (compiler-inserted) is sufficient.
    auto ldswrite = [&](v2f (&arr)[16]) {
        static_for<8>([&](auto kI) {
            constexpr int k8 = kI.value;
            lds4[waddr[k8]] = make_float4(arr[2*k8].x, arr[2*k8].y,
                                          arr[2*k8+1].x, arr[2*k8+1].y);
        });
    };
    // acc = (h*H) applied to the LDS-resident complex vector (packed r,i)
    auto stencil = [&]() {
        static_for<16>([&](auto kI) { acc[kI.value].x = 0.f; acc[kI.value].y = 0.f; });
        static_for<28>([&](auto gI) {
            constexpr int g = gI.value;
            float4 q = lds4[raddr[g]];
            v2f e0; e0.x = q.x; e0.y = q.y;
            v2f e1; e1.x = q.z; e1.y = q.w;
            static_for<16>([&](auto kI) {
                constexpr int k = kI.value;
                // window point j covers d = 16L-20+j ; tap distance = j-20-k
                constexpr int id0 = cidx(2*g     - 20 - k);
                constexpr int id1 = cidx(2*g + 1 - 20 - k);
                if constexpr (id0 >= 0) acc[k] += cs[id0] * e0;
                if constexpr (id1 >= 0) acc[k] += cs[id1] * e1;
            });
        });
    };

    ldswrite(cur);
    stencil();
    // rhs b = (I - i*h*H) rot : b_r = rot_r + hH(rot_i) ; b_i = rot_i - hH(rot_r)
    static_for<16>([&](auto kI) {
        constexpr int k = kI.value;
        b[k].x = cur[k].x + acc[k].y;
        b[k].y = cur[k].y - acc[k].x;
    });
    ldswrite(b);   // t0 = b

    // Horner: t <- b - i*h*H t  ==> t_r = b_r + hH(t_i), t_i = b_i - hH(t_r)
    #pragma unroll 1
    for (int itn = 0; itn < KSTEPS; ++itn) {
        stencil();
        static_for<16>([&](auto kI) {
            constexpr int k = kI.value;
            t[k].x = b[k].x + acc[k].y;
            t[k].y = b[k].y - acc[k].x;
        });
        if (itn != KSTEPS - 1) ldswrite(t);
    }

    // ---- store interleaved (r,i) pairs: 32 contiguous values at 32L ----
    if (isbf) {
        unsigned short* po = (unsigned short*)out + (size_t)sys*2048 + lane*32;
        uint4* po4 = (uint4*)po;
        static_for<4>([&](auto hI) {
            constexpr int h = hI.value;
            uint4 v;
            v.x = f2bf(t[4*h+0].x) | (f2bf(t[4*h+0].y) << 16);
            v.y = f2bf(t[4*h+1].x) | (f2bf(t[4*h+1].y) << 16);
            v.z = f2bf(t[4*h+2].x) | (f2bf(t[4*h+2].y) << 16);
            v.w = f2bf(t[4*h+3].x) | (f2bf(t[4*h+3].y) << 16);
            po4[h] = v;
        });
    } else {
        float* po = (float*)out + (size_t)sys*2048 + lane*32;
        static_for<8>([&](auto kI) {
            constexpr int k8 = kI.value;
            *(float4*)(po + 4*k8) = make_float4(t[2*k8].x, t[2*k8].y,
                                                t[2*k8+1].x, t[2*k8+1].y);
        });
    }
}

extern "C" void kernel_launch(void* const* d_in, const int* in_sizes, int n_in,
                              void* d_out, int out_size, void* d_ws, size_t ws_size,
                              hipStream_t stream)
{
    (void)in_sizes; (void)n_in; (void)out_size; (void)ws_size;
    detect_dtype<<<dim3(1), dim3(64), 0, stream>>>((const unsigned int*)d_in[0], (int*)d_ws);
    cayley_main<<<dim3(4096), dim3(256), 0, stream>>>(d_in[0], d_in[1], d_in[2], d_in[3],
                                                      d_out, (const int*)d_ws);
}